// Round 3
// baseline (4161.857 us; speedup 1.0000x reference)
//
#include <hip/hip_runtime.h>
#include <hip/hip_bf16.h>

typedef __hip_bfloat16 bf16;
typedef __attribute__((ext_vector_type(8))) short s16x8;   // 8 bf16 (MFMA A/B frag)
typedef __attribute__((ext_vector_type(4))) float f32x4;   // MFMA C/D frag
typedef __attribute__((ext_vector_type(4))) int   i32x4;

#define BATCH   64
#define SEQ     256
#define HID     1024
#define GATES   4096
#define NWG     256
#define THREADS 512          // 8 waves: 0-3 x-GEMM, 4-7 h-GEMM (task split)
#define UNITS   8            // hidden units per WG
#define NCOLS   32           // gate columns per WG (4 gates x 8 units)
#define ROWSTRIDE 2056       // 2048 K + 8 pad elems (LDS bank de-alias)
#define GSTRIDE 36           // gates LDS row stride (bank = 4*row+col: near-perfect)
#define BH      (BATCH * HID)

#define H0_SLOTS 4           // layer0 h ring (lets layer0 run ahead)
#define H1_SLOTS 2
#define FLAG_ELEMS ((size_t)6 * BH)            // flags start after h slots (bf16 elems)
#define WS_BYTES  (FLAG_ELEMS * 2 + 256 * 4)   // 786,432 + 1,024 per-WG epoch flags

#define OUT_HN  ((size_t)BATCH * SEQ * HID)
#define OUT_CN  (OUT_HN + 2ull * BATCH * HID)

// fp32 -> bf16 bits, round-to-nearest-even
__device__ __forceinline__ short f2bf(float f) {
    unsigned int u = __builtin_bit_cast(unsigned int, f);
    u = (u + 0x7fffu + ((u >> 16) & 1u)) >> 16;
    return (short)u;
}

// GEMM slice over K=1024, h loads at device coherent point (sc0 sc1: bypass L1+L2).
// Single base address + immediate offsets, 4 groups of 8 loads pipelined with
// counted vmcnt -> ~96 live h VGPRs, one latency exposure. sched_barrier after
// each waitcnt (rule #18).
#define MM8(B0) \
    _Pragma("unroll") \
    for (int kk = (B0); kk < (B0) + 8; ++kk) { \
        s16x8 b0 = *(const s16x8*)(s0 + kk * 32); \
        s16x8 b1 = *(const s16x8*)(s1 + kk * 32); \
        s16x8 av = __builtin_bit_cast(s16x8, h[kk]); \
        a0 = __builtin_amdgcn_mfma_f32_16x16x32_bf16(av, b0, a0, 0, 0, 0); \
        a1 = __builtin_amdgcn_mfma_f32_16x16x32_bf16(av, b1, a1, 0, 0, 0); \
    }

__device__ __forceinline__ void gemm_bt(const bf16* xrow, const bf16* s0, const bf16* s1,
                                        f32x4& a0, f32x4& a1)
{
    i32x4 h[32];
#define LD(i, OFF) asm volatile("global_load_dwordx4 %0, %1, off offset:" OFF " sc0 sc1" \
                                : "=v"(h[i]) : "v"(xrow))
    LD(0, "0");    LD(1, "64");   LD(2, "128");  LD(3, "192");
    LD(4, "256");  LD(5, "320");  LD(6, "384");  LD(7, "448");
    LD(8, "512");  LD(9, "576");  LD(10, "640"); LD(11, "704");
    LD(12, "768"); LD(13, "832"); LD(14, "896"); LD(15, "960");
    LD(16, "1024"); LD(17, "1088"); LD(18, "1152"); LD(19, "1216");
    LD(20, "1280"); LD(21, "1344"); LD(22, "1408"); LD(23, "1472");
    asm volatile("s_waitcnt vmcnt(16)"); __builtin_amdgcn_sched_barrier(0);
    MM8(0)
    LD(24, "1536"); LD(25, "1600"); LD(26, "1664"); LD(27, "1728");
    LD(28, "1792"); LD(29, "1856"); LD(30, "1920"); LD(31, "1984");
    asm volatile("s_waitcnt vmcnt(16)"); __builtin_amdgcn_sched_barrier(0);
    MM8(8)
    asm volatile("s_waitcnt vmcnt(8)");  __builtin_amdgcn_sched_barrier(0);
    MM8(16)
    asm volatile("s_waitcnt vmcnt(0)");  __builtin_amdgcn_sched_barrier(0);
    MM8(24)
#undef LD
}

// Per-WAVE poll (no barrier): lane l watches flags[l] and flags[64+l] of one
// layer's 128 per-WG epochs; exits when ALL >= tgt.
__device__ __forceinline__ void wave_poll(unsigned int* f, int tgt) {
    if (tgt <= 0) return;
    const int l = threadIdx.x & 63;
    unsigned int* p0 = f + l;
    unsigned int* p1 = f + 64 + l;
    for (;;) {
        int a = (int)__hip_atomic_load(p0, __ATOMIC_RELAXED, __HIP_MEMORY_SCOPE_AGENT);
        int b = (int)__hip_atomic_load(p1, __ATOMIC_RELAXED, __HIP_MEMORY_SCOPE_AGENT);
        if (__all((a >= tgt) && (b >= tgt))) break;
        __builtin_amdgcn_s_sleep(1);
    }
    asm volatile("" ::: "memory");
}

__global__ void ws_init(unsigned int* p, int n) {
    for (int i = blockIdx.x * blockDim.x + threadIdx.x; i < n; i += gridDim.x * blockDim.x)
        p[i] = 0u;
}

__global__ void __launch_bounds__(THREADS, 1)
lstm_enc(const int* __restrict__ src, const float* __restrict__ Wemb,
         const float* __restrict__ Wih, const float* __restrict__ Whh,
         const float* __restrict__ bih, const float* __restrict__ bhh,
         float* __restrict__ out, bf16* __restrict__ hbuf)
{
    __shared__ __align__(16) bf16 slab[NCOLS][ROWSTRIDE];   // 131,584 B (persists)
    __shared__ float gx[BATCH][GSTRIDE];                    // x-GEMM partials, 9,216 B
    __shared__ float gh[BATCH][GSTRIDE];                    // h-GEMM partials, 9,216 B
    __shared__ float bias[NCOLS];

    const int wg    = blockIdx.x;
    const int layer = wg >> 7;                 // 0-127: layer0, 128-255: layer1
    const int wgl   = wg & 127;
    const int j0    = wgl * UNITS;
    const int tid   = threadIdx.x;
    const int lane  = tid & 63;
    const int wave  = tid >> 6;                // 0-7
    const int grpB  = wave >> 2;               // 0: x-GEMM group, 1: h-GEMM group
    const int w4    = wave & 3;                // wave index within group
    const int m     = lane & 15;
    const int kq    = (lane >> 4) * 8;
    const int b_a   = w4 * 16 + m;             // batch row this lane loads for A

    // ---- weight slab: rows = [i8|f8|g8|o8], K = [W_ih row | W_hh row], fp32->bf16 ----
    for (int r = (tid >> 8); r < NCOLS; r += 2) {
        int g = r >> 3, u = r & 7;
        size_t grow = (size_t)layer * GATES * HID + (size_t)(g * HID + j0 + u) * HID;
        int k = (tid & 255) * 8;               // 256 threads x 8 = 2048 exact
        const float* s = (k < HID) ? (Wih + grow + k) : (Whh + grow + (k - HID));
        s16x8 v;
#pragma unroll
        for (int j = 0; j < 8; ++j) v[j] = f2bf(s[j]);
        *(s16x8*)&slab[r][k] = v;
    }
    if (tid < NCOLS) {
        int g = tid >> 3, u = tid & 7;
        int off = layer * GATES + g * HID + j0 + u;
        bias[tid] = bih[off] + bhh[off];
    }
    __syncthreads();

    bf16* h0 = hbuf;                           // [4][B][H] ring
    bf16* h1 = hbuf + H0_SLOTS * BH;           // [2][B][H] ring
    unsigned int* flags = (unsigned int*)(hbuf + FLAG_ELEMS);  // per-WG epoch counters
    unsigned int* f0 = flags;                  // layer0 epochs [0..127]
    unsigned int* f1 = flags + 128;            // layer1 epochs [0..127]

    // epilogue mapping: thread -> (bb = tid>>3, u0 = tid&7); 1 unit, c in register
    const int bb = tid >> 3;
    const int u0 = tid & 7;
    float c_st = 0.f;

    int sv = (layer == 0 && grpB == 0) ? src[b_a * SEQ] : 0;   // prefetched token

    for (int t = 0; t < SEQ; ++t) {
        f32x4 acc0 = {0.f, 0.f, 0.f, 0.f};
        f32x4 acc1 = {0.f, 0.f, 0.f, 0.f};

        if (grpB == 0) {
            // ================== x-path (waves 0-3) ==================
            if (layer == 0) {
                // embedding x-GEMM: no cross-WG dep. Ring-protect poll after
                // (L1 done t-4 before our epilogue overwrites h0 slot t&3).
                const float* xF = Wemb + (size_t)sv * HID + kq;
                if (t + 1 < SEQ) sv = src[b_a * SEQ + t + 1];
#pragma unroll
                for (int c = 0; c < 4; ++c) {
                    f32x4 xv[16];
#pragma unroll
                    for (int i = 0; i < 8; ++i) {
                        const float* p = xF + (c * 8 + i) * 32;
                        xv[2 * i]     = *(const f32x4*)p;
                        xv[2 * i + 1] = *(const f32x4*)(p + 4);
                    }
#pragma unroll
                    for (int i = 0; i < 8; ++i) {
                        const int k = (c * 8 + i) * 32 + kq;
                        s16x8 af;
#pragma unroll
                        for (int j = 0; j < 4; ++j) {
                            af[j]     = f2bf(xv[2 * i][j]);
                            af[4 + j] = f2bf(xv[2 * i + 1][j]);
                        }
                        s16x8 b0 = *(const s16x8*)&slab[m][k];
                        s16x8 b1 = *(const s16x8*)&slab[16 + m][k];
                        acc0 = __builtin_amdgcn_mfma_f32_16x16x32_bf16(af, b0, acc0, 0, 0, 0);
                        acc1 = __builtin_amdgcn_mfma_f32_16x16x32_bf16(af, b1, acc1, 0, 0, 0);
                    }
                }
                wave_poll(f1, t - 3);          // h0 ring protect (slack 3, rarely binds)
            } else {
                wave_poll(f0, t + 1);          // L0 finished step t -> h0[t] readable
                gemm_bt(h0 + (size_t)(t & (H0_SLOTS - 1)) * BH + b_a * HID + kq,
                        &slab[m][kq], &slab[16 + m][kq], acc0, acc1);
            }
            const int rowg = w4 * 16 + (lane >> 4) * 4;
#pragma unroll
            for (int r = 0; r < 4; ++r) {
                gx[rowg + r][m]      = acc0[r];
                gx[rowg + r][16 + m] = acc1[r];
            }
        } else {
            // ================== h-path (waves 4-7) ==================
            wave_poll(layer == 0 ? f0 : f1, t);    // own layer done t-1
            bf16* hrow = ((layer == 0)
                ? h0 + (size_t)((t - 1) & (H0_SLOTS - 1)) * BH
                : h1 + (size_t)((t - 1) & (H1_SLOTS - 1)) * BH) + b_a * HID + kq;
            gemm_bt(hrow, &slab[m][HID + kq], &slab[16 + m][HID + kq], acc0, acc1);
            const int rowg = w4 * 16 + (lane >> 4) * 4;
#pragma unroll
            for (int r = 0; r < 4; ++r) {
                gh[rowg + r][m]      = acc0[r];
                gh[rowg + r][16 + m] = acc1[r];
            }
        }
        __syncthreads();   // #1: gx+gh complete

        // ---- epilogue: 1 unit per thread, c-state in register ----
        float gi = gx[bb][u0]      + gh[bb][u0]      + bias[u0];
        float gf = gx[bb][u0 + 8]  + gh[bb][u0 + 8]  + bias[u0 + 8];
        float gg = gx[bb][u0 + 16] + gh[bb][u0 + 16] + bias[u0 + 16];
        float go = gx[bb][u0 + 24] + gh[bb][u0 + 24] + bias[u0 + 24];
        float si = 1.f / (1.f + __expf(-gi));
        float sf = 1.f / (1.f + __expf(-gf));
        float so = 1.f / (1.f + __expf(-go));
        c_st = sf * c_st + si * tanhf(gg);
        float h_v = so * tanhf(c_st);

        bf16* hw = ((layer == 0) ? h0 + (size_t)(t & (H0_SLOTS - 1)) * BH
                                 : h1 + (size_t)(t & (H1_SLOTS - 1)) * BH);
        __hip_atomic_store((unsigned short*)(hw + bb * HID + j0 + u0),
                           (unsigned short)f2bf(h_v),
                           __ATOMIC_RELAXED, __HIP_MEMORY_SCOPE_AGENT);

        __syncthreads();   // #2: drains vmcnt(0) -> all h stores at coherent point
        asm volatile("" ::: "memory");
        if (tid == 0)      // per-WG epoch store
            __hip_atomic_store(flags + wg, (unsigned int)(t + 1),
                               __ATOMIC_RELAXED, __HIP_MEMORY_SCOPE_AGENT);

        // ---- post-flag stores: off the recurrence critical path (HBM acks
        //      drain at next step's barrier, overlapped with polls/GEMMs) ----
        if (layer == 1)
            out[((size_t)bb * SEQ + t) * HID + j0 + u0] = h_v;
        if (t == SEQ - 1) {
            size_t o = ((size_t)layer * BATCH + bb) * HID + j0 + u0;
            out[OUT_HN + o] = h_v;
            out[OUT_CN + o] = c_st;
        }
    }
}

extern "C" void kernel_launch(void* const* d_in, const int* in_sizes, int n_in,
                              void* d_out, int out_size, void* d_ws, size_t ws_size,
                              hipStream_t stream) {
    const int*   src  = (const int*)d_in[0];
    const float* emb  = (const float*)d_in[1];
    const float* W_ih = (const float*)d_in[2];
    const float* W_hh = (const float*)d_in[3];
    const float* b_ih = (const float*)d_in[4];
    const float* b_hh = (const float*)d_in[5];
    float* out  = (float*)d_out;
    bf16*  hbuf = (bf16*)d_ws;                 // uses 787,456 B

    // zero h rings + flag words (ws is re-poisoned 0xAA before every replay;
    // ws_init's dispatch-end release flushes its L2 lines to the coherent point)
    unsigned int* wsp = (unsigned int*)d_ws;
    int n = (int)(WS_BYTES / 4);
    ws_init<<<256, 256, 0, stream>>>(wsp, n);

    void* args[] = {&src, &emb, &W_ih, &W_hh, &b_ih, &b_hh, &out, &hbuf};
    hipLaunchCooperativeKernel((void*)lstm_enc, dim3(NWG), dim3(THREADS),
                               args, 0, stream);
}